// Round 5
// baseline (1342.735 us; speedup 1.0000x reference)
//
#include <hip/hip_runtime.h>
#include <hip/hip_cooperative_groups.h>

namespace cg = cooperative_groups;

typedef unsigned short ushort_t;
typedef __attribute__((ext_vector_type(8))) short short8;
typedef __attribute__((ext_vector_type(4))) float floatx4;

#define NN 96
#define BSZ 16
#define TSTEP 12
#define JSPLIT 4
#define JPW 24   /* 96 / JSPLIT */
#define NBLK 384 /* JSPLIT * 16 * 6 — needs only 2 blocks/CU co-residency */

// workspace offsets (bytes)
#define OFF_S     0u
#define OFF_R     393216u
#define OFF_E     786432u
#define OFF_P     860160u
#define OFF_HALL  2433024u
#define OFF_WSWZ  7151616u

static __device__ __forceinline__ short f2bf(float f){
    union { float f; unsigned u; } v; v.f = f;
    unsigned u = v.u;
    u += 0x7fffu + ((u >> 16) & 1u);   // RNE
    return (short)(u >> 16);
}
static __device__ __forceinline__ float fast_tanh(float x){
    x = fminf(20.f, fmaxf(-20.f, x));
    float p = __expf(2.f * x);
    return (p - 1.f) * __builtin_amdgcn_rcpf(p + 1.f);
}
static __device__ __forceinline__ float fast_sigmoid(float x){
    x = fminf(30.f, fmaxf(-30.f, x));
    float p = __expf(-x);
    return __builtin_amdgcn_rcpf(1.f + p);
}
static __device__ __forceinline__ void zero4(floatx4* a){
    floatx4 z = {0.f,0.f,0.f,0.f};
    a[0]=z; a[1]=z; a[2]=z; a[3]=z;
}
// read A-fragments (16x64, row m = lane&15, k = quad*8+jj) from LDS tile, stride 68
static __device__ __forceinline__ void buildA(const float* sM, int col, int quad, short8& a0, short8& a1){
    floatx4 f0 = *(const floatx4*)&sM[col*68 + quad*8];
    floatx4 f1 = *(const floatx4*)&sM[col*68 + quad*8 + 4];
    floatx4 f2 = *(const floatx4*)&sM[col*68 + 32 + quad*8];
    floatx4 f3 = *(const floatx4*)&sM[col*68 + 32 + quad*8 + 4];
    #pragma unroll
    for (int jj = 0; jj < 4; jj++){
        a0[jj]   = f2bf(f0[jj]);
        a0[4+jj] = f2bf(f1[jj]);
        a1[jj]   = f2bf(f2[jj]);
        a1[4+jj] = f2bf(f3[jj]);
    }
}
// 16x64 = (16x64) @ (64x64), B pre-swizzled fragment-major; accumulates into acc[4]
static __device__ __forceinline__ void mm16(short8 a0, short8 a1, const short8* wzm, int l, floatx4* acc){
    #pragma unroll
    for (int nt = 0; nt < 4; nt++){
        short8 b0 = wzm[nt*64 + l];
        short8 b1 = wzm[(4 + nt)*64 + l];
        acc[nt] = __builtin_amdgcn_mfma_f32_16x16x32_bf16(a0, b0, acc[nt], 0, 0, 0);
        acc[nt] = __builtin_amdgcn_mfma_f32_16x16x32_bf16(a1, b1, acc[nt], 0, 0, 0);
    }
}

struct MsgSmem {
    float sS[JPW*64];
    float sR[16*68];
    float sAdj[16*JPW];
    float sAgg[4][16*68];
};

// ---------------------------------------------------------------------------
// msg phase: partial[js][b][i][d] = (1/N) sum_{j in chunk} adj[b,i,j] *
//   tanh( tanh(S[b,j] + R[b,i] + b1) @ Wmsg2 + b2 )[d]
// one (js,b,it) unit per block; 4 waves x 6 j's.
// ---------------------------------------------------------------------------
static __device__ void msg_phase(MsgSmem& sh, int tid, int t, int js, int b, int it,
    const float* __restrict__ adj, const float* __restrict__ b1in, const float* __restrict__ b2in,
    const float* __restrict__ Sg, const float* __restrict__ Rg,
    const short8* __restrict__ wz, float* __restrict__ partial)
{
    const int w = tid >> 6, l = tid & 63;
    const int quad = l >> 4, col = l & 15;
    const int j0 = js * JPW;

    if (t > 0) {
        for (int q = tid; q < JPW*16; q += 256) {
            int row = q >> 4, c4 = (q & 15) * 4;
            *(floatx4*)&sh.sS[row*64 + c4] = *(const floatx4*)&Sg[(b*NN + j0 + row)*64 + c4];
        }
        for (int q = tid; q < 16*16; q += 256) {
            int row = q >> 4, c4 = (q & 15) * 4;
            floatx4 r4 = *(const floatx4*)&Rg[(b*NN + it*16 + row)*64 + c4];
            floatx4 b4 = *(const floatx4*)&b1in[c4];
            *(floatx4*)&sh.sR[row*68 + c4] = r4 + b4;
        }
    } else {
        for (int q = tid; q < JPW*16; q += 256) {
            int row = q >> 4, c4 = (q & 15) * 4;
            floatx4 z = {0.f,0.f,0.f,0.f};
            *(floatx4*)&sh.sS[row*64 + c4] = z;
        }
        for (int q = tid; q < 16*16; q += 256) {
            int row = q >> 4, c4 = (q & 15) * 4;
            *(floatx4*)&sh.sR[row*68 + c4] = *(const floatx4*)&b1in[c4];
        }
    }
    for (int q = tid; q < 16*JPW; q += 256) {
        int i = q / JPW, j = q % JPW;
        sh.sAdj[q] = adj[(b*NN + it*16 + i)*NN + j0 + j];
    }
    short8 w2f[2][4];
    #pragma unroll
    for (int kc = 0; kc < 2; kc++)
      #pragma unroll
      for (int nt = 0; nt < 4; nt++)
        w2f[kc][nt] = wz[(kc*4 + nt)*64 + l];
    float b2v[4];
    #pragma unroll
    for (int nt = 0; nt < 4; nt++) b2v[nt] = b2in[nt*16 + col];
    __syncthreads();

    float rbv[16];
    #pragma unroll
    for (int c = 0; c < 4; c++)
        *(floatx4*)&rbv[c*4] = *(const floatx4*)&sh.sR[col*68 + (c>>1)*32 + quad*8 + (c&1)*4];

    float agg[4][4];
    #pragma unroll
    for (int nt=0;nt<4;nt++)
      #pragma unroll
      for (int r=0;r<4;r++) agg[nt][r] = 0.f;

    for (int c = 0; c < 6; c++) {
        int jl = w*6 + c;
        float sv[16];
        #pragma unroll
        for (int cc = 0; cc < 4; cc++)
            *(floatx4*)&sv[cc*4] = *(const floatx4*)&sh.sS[jl*64 + (cc>>1)*32 + quad*8 + (cc&1)*4];
        short8 a0, a1;
        #pragma unroll
        for (int e = 0; e < 8; e++) {
            a0[e] = f2bf(fast_tanh(sv[e]   + rbv[e]));
            a1[e] = f2bf(fast_tanh(sv[8+e] + rbv[8+e]));
        }
        floatx4 acc[4];
        zero4(acc);
        #pragma unroll
        for (int nt = 0; nt < 4; nt++) {
            acc[nt] = __builtin_amdgcn_mfma_f32_16x16x32_bf16(a0, w2f[0][nt], acc[nt], 0,0,0);
            acc[nt] = __builtin_amdgcn_mfma_f32_16x16x32_bf16(a1, w2f[1][nt], acc[nt], 0,0,0);
        }
        float adjv[4];
        #pragma unroll
        for (int r = 0; r < 4; r++) adjv[r] = sh.sAdj[(quad*4 + r)*JPW + jl];
        #pragma unroll
        for (int nt = 0; nt < 4; nt++)
          #pragma unroll
          for (int r = 0; r < 4; r++)
            agg[nt][r] += adjv[r] * fast_tanh(acc[nt][r] + b2v[nt]);
    }
    #pragma unroll
    for (int nt = 0; nt < 4; nt++)
      #pragma unroll
      for (int r = 0; r < 4; r++)
        sh.sAgg[w][(quad*4 + r)*68 + nt*16 + col] = agg[nt][r];
    __syncthreads();
    {
        int i = tid >> 4, k4 = (tid & 15) * 4;
        floatx4 s0 = *(const floatx4*)&sh.sAgg[0][i*68 + k4];
        floatx4 s1 = *(const floatx4*)&sh.sAgg[1][i*68 + k4];
        floatx4 s2 = *(const floatx4*)&sh.sAgg[2][i*68 + k4];
        floatx4 s3 = *(const floatx4*)&sh.sAgg[3][i*68 + k4];
        floatx4 o = ((s0 + s1) + (s2 + s3)) * (1.f/96.f);
        *(floatx4*)&partial[((js*BSZ + b)*NN + it*16 + i)*64 + k4] = o;
    }
}

// ---------------------------------------------------------------------------
// gru phase for one (b,it) tile, 256 threads / 4 waves.
// h(t+1) = GRU(agg(t), E[skill_t], h(t)); writes Hall[t], Sg, Rg.
// ---------------------------------------------------------------------------
static __device__ void gru_phase(float (*sAgg)[16*68], int tid, int t, int b, int it,
    const int* __restrict__ skills, const float* __restrict__ partial,
    const float* __restrict__ Ef, const short8* __restrict__ wz,
    float* __restrict__ Hall, float* __restrict__ Sg, float* __restrict__ Rg)
{
    const int w = tid >> 6, l = tid & 63;
    const int quad = l >> 4, col = l & 15;
    const int gi_row = tid >> 4, gd4 = (tid & 15) * 4;

    floatx4 a = {0.f,0.f,0.f,0.f};
    #pragma unroll
    for (int p = 0; p < JSPLIT; p++)
        a += *(const floatx4*)&partial[((p*BSZ + b)*NN + it*16 + gi_row)*64 + gd4];
    *(floatx4*)&sAgg[0][gi_row*68 + gd4] = a;
    __syncthreads();
    if (w < 3) {          // Ar / Ai / Ah in parallel, one matmul per wave
        short8 A0, A1;
        buildA(sAgg[0], col, quad, A0, A1);
        floatx4 M[4]; zero4(M);
        mm16(A0, A1, wz + (1+w)*512, l, M);
        #pragma unroll
        for (int nt = 0; nt < 4; nt++)
          #pragma unroll
          for (int r = 0; r < 4; r++)
            sAgg[1+w][(quad*4 + r)*68 + nt*16 + col] = M[nt][r];
    }
    __syncthreads();
    {                     // elementwise GRU across all 256 threads
        int s = skills[b*13 + t];
        floatx4 ar = *(const floatx4*)&sAgg[1][gi_row*68 + gd4];
        floatx4 ai = *(const floatx4*)&sAgg[2][gi_row*68 + gd4];
        floatx4 ah = *(const floatx4*)&sAgg[3][gi_row*68 + gd4];
        floatx4 er = *(const floatx4*)&Ef[0*6144 + s*64 + gd4];
        floatx4 ei = *(const floatx4*)&Ef[1*6144 + s*64 + gd4];
        floatx4 en = *(const floatx4*)&Ef[2*6144 + s*64 + gd4];
        floatx4 hold = {0.f,0.f,0.f,0.f};
        if (t > 0)
            hold = *(const floatx4*)&Hall[(((t-1)*BSZ + b)*NN + it*16 + gi_row)*64 + gd4];
        floatx4 h;
        #pragma unroll
        for (int e = 0; e < 4; e++) {
            float gr  = fast_sigmoid(er[e] + ar[e]);
            float gi2 = fast_sigmoid(ei[e] + ai[e]);
            float nn2 = fast_tanh(en[e] + gr * ah[e]);
            h[e] = (1.f - gi2)*nn2 + gi2*hold[e];
        }
        *(floatx4*)&Hall[((t*BSZ + b)*NN + it*16 + gi_row)*64 + gd4] = h;
        *(floatx4*)&sAgg[0][gi_row*68 + gd4] = h;
    }
    __syncthreads();
    if (w < 2) {          // S (w==0) and R (w==1) in parallel
        short8 h0, h1;
        buildA(sAgg[0], col, quad, h0, h1);
        floatx4 M[4]; zero4(M);
        mm16(h0, h1, wz + (4+w)*512, l, M);
        float* dst = (w == 0) ? Sg : Rg;
        #pragma unroll
        for (int nt = 0; nt < 4; nt++)
          #pragma unroll
          for (int r = 0; r < 4; r++)
            dst[(b*NN + it*16 + quad*4 + r)*64 + nt*16 + col] = M[nt][r];
    }
}

// ---------------------------------------------------------------------------
// one tile's 3-layer output MLP, one wave, own LDS tile sT (16x68).
// ---------------------------------------------------------------------------
static __device__ void mlp_tile(float* sT, int l, bool valid, int t2, int b2, int it2,
    const short8* __restrict__ wz,
    const float* __restrict__ bo1, const float* __restrict__ bo2, const float* __restrict__ bo3,
    const float* __restrict__ Hall, float* __restrict__ out)
{
    const int quad = l >> 4, col = l & 15;
    short8 x0, x1;
    floatx4 O[4];
    if (valid) {
        const float* hb = &Hall[((t2*BSZ + b2)*NN + it2*16 + col)*64];
        floatx4 f0 = *(const floatx4*)&hb[quad*8];
        floatx4 f1 = *(const floatx4*)&hb[quad*8 + 4];
        floatx4 f2 = *(const floatx4*)&hb[32 + quad*8];
        floatx4 f3 = *(const floatx4*)&hb[32 + quad*8 + 4];
        #pragma unroll
        for (int jj = 0; jj < 4; jj++){
            x0[jj]   = f2bf(f0[jj]);
            x0[4+jj] = f2bf(f1[jj]);
            x1[jj]   = f2bf(f2[jj]);
            x1[4+jj] = f2bf(f3[jj]);
        }
        zero4(O);
        mm16(x0, x1, wz + 6*512, l, O);
        #pragma unroll
        for (int nt = 0; nt < 4; nt++)
          #pragma unroll
          for (int r = 0; r < 4; r++)
            sT[(quad*4 + r)*68 + nt*16 + col] = fmaxf(0.f, O[nt][r] + bo1[nt*16 + col]);
    }
    __syncthreads();
    if (valid) {
        buildA(sT, col, quad, x0, x1);
        zero4(O);
        mm16(x0, x1, wz + 7*512, l, O);
        #pragma unroll
        for (int nt = 0; nt < 4; nt++)
          #pragma unroll
          for (int r = 0; r < 4; r++)
            sT[(quad*4 + r)*68 + nt*16 + col] = fmaxf(0.f, O[nt][r] + bo2[nt*16 + col]);
    }
    __syncthreads();
    if (valid) {
        buildA(sT, col, quad, x0, x1);
        zero4(O);
        mm16(x0, x1, wz + 8*512, l, O);
        #pragma unroll
        for (int nt = 0; nt < 4; nt++)
          #pragma unroll
          for (int r = 0; r < 4; r++) {
            int d = nt*16 + col;
            int row = quad*4 + r;
            out[((b2*TSTEP + t2)*NN + it2*16 + row)*64 + d] = O[nt][r] + bo3[d];
          }
    }
}

// ---------------------------------------------------------------------------
// init: compute E_* = emb @ W_i* + b_* (fp32), pre-swizzle 9 weight matrices
// into bf16 B-fragment order: flat = ((kc*4+nt)*64 + lane)*8 + jj
// ---------------------------------------------------------------------------
__global__ __launch_bounds__(256) void k_init(
    const float* __restrict__ emb, const float* __restrict__ Wmsg1,
    const float* __restrict__ Wmsg2,
    const float* __restrict__ Whr, const float* __restrict__ Whi, const float* __restrict__ Whh,
    const float* __restrict__ Wir, const float* __restrict__ bir,
    const float* __restrict__ Wii, const float* __restrict__ bii,
    const float* __restrict__ Win, const float* __restrict__ bin,
    const float* __restrict__ Wo1, const float* __restrict__ Wo2, const float* __restrict__ Wo3,
    float* __restrict__ Ef, ushort_t* __restrict__ wswz)
{
    int wg = blockIdx.x, tid = threadIdx.x;
    if (wg < 72) {                        // E matrices: 3 * 96 * 64
        int flat = wg*256 + tid;
        int m = flat / 6144; int r = flat % 6144; int s = r >> 6; int d = r & 63;
        const float* W = (m==0)? Wir : (m==1)? Wii : Win;
        const float* B = (m==0)? bir : (m==1)? bii : bin;
        float acc = B[d];
        #pragma unroll 8
        for (int k = 0; k < 64; k++)
            acc += emb[s*64 + k] * W[k*64 + d];
        Ef[flat] = acc;
    } else {                              // swizzle: 9 * 4096
        int flat = (wg - 72)*256 + tid;
        int m = flat >> 12; int q = flat & 4095;
        int jj = q & 7, lane = (q >> 3) & 63, nt = (q >> 9) & 3, kc = q >> 11;
        int k = kc*32 + ((lane >> 4) << 3) + jj;
        int n = nt*16 + (lane & 15);
        const float* src; int idx = k*64 + n;
        switch (m) {
          case 0: src = Wmsg2; break;
          case 1: src = Whr;  break;
          case 2: src = Whi;  break;
          case 3: src = Whh;  break;
          case 4: src = Wmsg1; break;
          case 5: src = Wmsg1; idx = (64 + k)*64 + n; break;
          case 6: src = Wo1; break;
          case 7: src = Wo2; break;
          default: src = Wo3; break;
        }
        wswz[flat] = (ushort_t)f2bf(src[idx]);
    }
}

// ---------------------------------------------------------------------------
// cooperative persistent kernel: 384 blocks (2/CU co-residency max needed).
// ---------------------------------------------------------------------------
__global__ __launch_bounds__(256, 2) void k_loop(
    const int* __restrict__ skills, const float* __restrict__ adj,
    const float* __restrict__ b1in, const float* __restrict__ b2in,
    const float* __restrict__ bo1, const float* __restrict__ bo2, const float* __restrict__ bo3,
    const float* __restrict__ Ef, const ushort_t* __restrict__ wswz,
    float* __restrict__ Sg, float* __restrict__ Rg, float* __restrict__ partial,
    float* __restrict__ Hall, float* __restrict__ out)
{
    cg::grid_group gg = cg::this_grid();
    __shared__ MsgSmem sh;
    const int blk = blockIdx.x;
    const int js = blk / 96, rem = blk % 96, b = rem / 6, it = rem % 6;
    const int tid = threadIdx.x, w = tid >> 6, l = tid & 63;
    const short8* wz = (const short8*)wswz;

    for (int t = 0; t < TSTEP; t++) {
        msg_phase(sh, tid, t, js, b, it, adj, b1in, b2in, Sg, Rg, wz, partial);
        gg.sync();
        if (js == 0)
            gru_phase(sh.sAgg, tid, t, b, it, skills, partial, Ef, wz, Hall, Sg, Rg);
        gg.sync();
    }
    // deferred output MLPs: 1152 tile-MLPs over 1536 waves
    int g = blk*4 + w;
    bool valid = (g < TSTEP*96);
    int t2 = g / 96, r2 = g % 96, b2 = r2 / 6, it2 = r2 % 6;
    mlp_tile(sh.sAgg[w], l, valid, t2, b2, it2, wz, bo1, bo2, bo3, Hall, out);
}

// ---------------------------------------------------------------------------
// fallback discrete kernels (same device functions)
// ---------------------------------------------------------------------------
__global__ __launch_bounds__(256, 2) void k_msg_f(
    const float* __restrict__ adj, const float* __restrict__ b1in, const float* __restrict__ b2in,
    const float* __restrict__ Sg, const float* __restrict__ Rg,
    const ushort_t* __restrict__ wswz, float* __restrict__ partial, int t)
{
    __shared__ MsgSmem sh;
    const int blk = blockIdx.x;
    const int js = blk / 96, rem = blk % 96, b = rem / 6, it = rem % 6;
    msg_phase(sh, threadIdx.x, t, js, b, it, adj, b1in, b2in, Sg, Rg, (const short8*)wswz, partial);
}

__global__ __launch_bounds__(256) void k_gru_f(
    const int* __restrict__ skills, const float* __restrict__ partial,
    const float* __restrict__ Ef, const ushort_t* __restrict__ wswz,
    float* __restrict__ Hall, float* __restrict__ Sg, float* __restrict__ Rg, int t)
{
    __shared__ float sAgg[4][16*68];
    const int b = blockIdx.x / 6, it = blockIdx.x % 6;
    gru_phase(sAgg, threadIdx.x, t, b, it, skills, partial, Ef, (const short8*)wswz, Hall, Sg, Rg);
}

__global__ __launch_bounds__(256) void k_mlp_f(
    const ushort_t* __restrict__ wswz,
    const float* __restrict__ bo1, const float* __restrict__ bo2, const float* __restrict__ bo3,
    const float* __restrict__ Hall, float* __restrict__ out)
{
    __shared__ float sT[4][16*68];
    const int w = threadIdx.x >> 6, l = threadIdx.x & 63;
    const int g = blockIdx.x*4 + w;    // grid 288 -> g < 1152, always valid
    const int t2 = g / 96, r2 = g % 96, b2 = r2 / 6, it2 = r2 % 6;
    mlp_tile(sT[w], l, true, t2, b2, it2, (const short8*)wswz, bo1, bo2, bo3, Hall, out);
}

extern "C" void kernel_launch(void* const* d_in, const int* in_sizes, int n_in,
                              void* d_out, int out_size, void* d_ws, size_t ws_size,
                              hipStream_t stream) {
    const int*   skills = (const int*)d_in[0];
    const float* adj    = (const float*)d_in[1];
    const float* emb    = (const float*)d_in[2];
    const float* Wmsg1  = (const float*)d_in[3];
    const float* b1     = (const float*)d_in[4];
    const float* Wmsg2  = (const float*)d_in[5];
    const float* b2     = (const float*)d_in[6];
    const float* Whr    = (const float*)d_in[7];
    const float* Whi    = (const float*)d_in[8];
    const float* Whh    = (const float*)d_in[9];
    const float* Wir    = (const float*)d_in[10];
    const float* bir    = (const float*)d_in[11];
    const float* Wii    = (const float*)d_in[12];
    const float* bii    = (const float*)d_in[13];
    const float* Win    = (const float*)d_in[14];
    const float* bin    = (const float*)d_in[15];
    const float* Wo1    = (const float*)d_in[16];
    const float* bo1    = (const float*)d_in[17];
    const float* Wo2    = (const float*)d_in[18];
    const float* bo2    = (const float*)d_in[19];
    const float* Wo3    = (const float*)d_in[20];
    const float* bo3    = (const float*)d_in[21];

    char* ws = (char*)d_ws;
    float*    Sg      = (float*)(ws + OFF_S);
    float*    Rg      = (float*)(ws + OFF_R);
    float*    Ef      = (float*)(ws + OFF_E);
    float*    partial = (float*)(ws + OFF_P);
    float*    Hall    = (float*)(ws + OFF_HALL);
    ushort_t* wswz    = (ushort_t*)(ws + OFF_WSWZ);
    float*    out     = (float*)d_out;

    k_init<<<dim3(216), dim3(256), 0, stream>>>(emb, Wmsg1, Wmsg2, Whr, Whi, Whh,
        Wir, bir, Wii, bii, Win, bin, Wo1, Wo2, Wo3, Ef, wswz);

    void* args[] = { (void*)&skills, (void*)&adj, (void*)&b1, (void*)&b2,
                     (void*)&bo1, (void*)&bo2, (void*)&bo3,
                     (void*)&Ef, (void*)&wswz, (void*)&Sg, (void*)&Rg,
                     (void*)&partial, (void*)&Hall, (void*)&out };
    hipError_t err = hipLaunchCooperativeKernel((const void*)k_loop, dim3(NBLK), dim3(256),
                                                args, 0, stream);
    if (err != hipSuccess) {
        // deterministic fallback: same phases as discrete kernels
        for (int t = 0; t < TSTEP; t++) {
            k_msg_f<<<dim3(NBLK), dim3(256), 0, stream>>>(adj, b1, b2, Sg, Rg, wswz, partial, t);
            k_gru_f<<<dim3(96), dim3(256), 0, stream>>>(skills, partial, Ef, wswz, Hall, Sg, Rg, t);
        }
        k_mlp_f<<<dim3(288), dim3(256), 0, stream>>>(wswz, bo1, bo2, bo3, Hall, out);
    }
}

// Round 6
// 512.647 us; speedup vs baseline: 2.6192x; 2.6192x over previous
//
#include <hip/hip_runtime.h>

typedef unsigned short ushort_t;
typedef __attribute__((ext_vector_type(8))) short short8;
typedef __attribute__((ext_vector_type(4))) float floatx4;

#define NN 96
#define BSZ 16
#define TSTEP 12
#define JSPLIT 8
#define JPW 12   /* 96 / JSPLIT */
#define NBLK 768 /* 8 x 16 x 6; co-resident at 3 blocks/CU (VGPR<=170, LDS 25.6KB) */

// workspace offsets (bytes)
#define OFF_FLAG  0u        /* pc[96] + sflag[96] ints */
#define OFF_S     1024u
#define OFF_R     394240u
#define OFF_E     787456u
#define OFF_P     861184u
#define OFF_HALL  4006912u
#define OFF_WSWZ  8725504u

static __device__ __forceinline__ short f2bf(float f){
    union { float f; unsigned u; } v; v.f = f;
    unsigned u = v.u;
    u += 0x7fffu + ((u >> 16) & 1u);   // RNE
    return (short)(u >> 16);
}
static __device__ __forceinline__ float fast_tanh(float x){
    x = fminf(20.f, fmaxf(-20.f, x));
    float p = __expf(2.f * x);
    return (p - 1.f) * __builtin_amdgcn_rcpf(p + 1.f);
}
static __device__ __forceinline__ float fast_sigmoid(float x){
    x = fminf(30.f, fmaxf(-30.f, x));
    float p = __expf(-x);
    return __builtin_amdgcn_rcpf(1.f + p);
}
static __device__ __forceinline__ void zero4(floatx4* a){
    floatx4 z = {0.f,0.f,0.f,0.f};
    a[0]=z; a[1]=z; a[2]=z; a[3]=z;
}
static __device__ __forceinline__ void wait_ge(int* f, int target){
    while (__hip_atomic_load(f, __ATOMIC_RELAXED, __HIP_MEMORY_SCOPE_AGENT) < target)
        __builtin_amdgcn_s_sleep(2);
}
// read A-fragments (16x64, row m = lane&15, k = quad*8+jj) from LDS tile, stride 68
static __device__ __forceinline__ void buildA(const float* sM, int col, int quad, short8& a0, short8& a1){
    floatx4 f0 = *(const floatx4*)&sM[col*68 + quad*8];
    floatx4 f1 = *(const floatx4*)&sM[col*68 + quad*8 + 4];
    floatx4 f2 = *(const floatx4*)&sM[col*68 + 32 + quad*8];
    floatx4 f3 = *(const floatx4*)&sM[col*68 + 32 + quad*8 + 4];
    #pragma unroll
    for (int jj = 0; jj < 4; jj++){
        a0[jj]   = f2bf(f0[jj]);
        a0[4+jj] = f2bf(f1[jj]);
        a1[jj]   = f2bf(f2[jj]);
        a1[4+jj] = f2bf(f3[jj]);
    }
}
// 16x64 = (16x64) @ (64x64), B pre-swizzled fragment-major; accumulates into acc[4]
static __device__ __forceinline__ void mm16(short8 a0, short8 a1, const short8* wzm, int l, floatx4* acc){
    #pragma unroll
    for (int nt = 0; nt < 4; nt++){
        short8 b0 = wzm[nt*64 + l];
        short8 b1 = wzm[(4 + nt)*64 + l];
        acc[nt] = __builtin_amdgcn_mfma_f32_16x16x32_bf16(a0, b0, acc[nt], 0, 0, 0);
        acc[nt] = __builtin_amdgcn_mfma_f32_16x16x32_bf16(a1, b1, acc[nt], 0, 0, 0);
    }
}

// ---------------------------------------------------------------------------
// init: zero flags, compute E_* = emb @ W_i* + b_* (fp32), pre-swizzle 9
// weight matrices into bf16 B-fragment order: flat = ((kc*4+nt)*64 + lane)*8 + jj
// ---------------------------------------------------------------------------
__global__ __launch_bounds__(256) void k_init(
    const float* __restrict__ emb, const float* __restrict__ Wmsg1,
    const float* __restrict__ Wmsg2,
    const float* __restrict__ Whr, const float* __restrict__ Whi, const float* __restrict__ Whh,
    const float* __restrict__ Wir, const float* __restrict__ bir,
    const float* __restrict__ Wii, const float* __restrict__ bii,
    const float* __restrict__ Win, const float* __restrict__ bin,
    const float* __restrict__ Wo1, const float* __restrict__ Wo2, const float* __restrict__ Wo3,
    int* __restrict__ flags, float* __restrict__ Ef, ushort_t* __restrict__ wswz)
{
    int wg = blockIdx.x, tid = threadIdx.x;
    if (wg == 0) {                        // zero pc[96] + sflag[96]
        if (tid < 192) flags[tid] = 0;
    } else if (wg < 73) {                 // E matrices: 3 * 96 * 64
        int flat = (wg - 1)*256 + tid;
        int m = flat / 6144; int r = flat % 6144; int s = r >> 6; int d = r & 63;
        const float* W = (m==0)? Wir : (m==1)? Wii : Win;
        const float* B = (m==0)? bir : (m==1)? bii : bin;
        float acc = B[d];
        #pragma unroll 8
        for (int k = 0; k < 64; k++)
            acc += emb[s*64 + k] * W[k*64 + d];
        Ef[flat] = acc;
    } else {                              // swizzle: 9 * 4096
        int flat = (wg - 73)*256 + tid;
        int m = flat >> 12; int q = flat & 4095;
        int jj = q & 7, lane = (q >> 3) & 63, nt = (q >> 9) & 3, kc = q >> 11;
        int k = kc*32 + ((lane >> 4) << 3) + jj;
        int n = nt*16 + (lane & 15);
        const float* src; int idx = k*64 + n;
        switch (m) {
          case 0: src = Wmsg2; break;
          case 1: src = Whr;  break;
          case 2: src = Whi;  break;
          case 3: src = Whh;  break;
          case 4: src = Wmsg1; break;
          case 5: src = Wmsg1; idx = (64 + k)*64 + n; break;
          case 6: src = Wo1; break;
          case 7: src = Wo2; break;
          default: src = Wo3; break;
        }
        wswz[flat] = (ushort_t)f2bf(src[idx]);
    }
}

// ---------------------------------------------------------------------------
// persistent kernel, flag-synced (no grid barriers). 768 blocks = 8(js) x
// 16(b) x 6(it), all co-resident (3/CU). Per step:
//   msg: wait sflag(S tiles, R tile) >= t; compute; store partial; pc += 1
//   GRU (js==0): wait pc >= 8(t+1); GRU; store Hall/Sg/Rg; sflag = t+1
// MLP tail: js<3 blocks wait sflag >= 12, each wave one (t,b,it) tile.
// ---------------------------------------------------------------------------
__global__ __launch_bounds__(256, 3) void k_loop(
    const int* __restrict__ skills, const float* __restrict__ adj,
    const float* __restrict__ b1in, const float* __restrict__ b2in,
    const float* __restrict__ bo1, const float* __restrict__ bo2, const float* __restrict__ bo3,
    const float* __restrict__ Ef, const ushort_t* __restrict__ wswz,
    float* __restrict__ Sg, float* __restrict__ Rg, float* __restrict__ partial,
    float* __restrict__ Hall, float* __restrict__ out,
    int* __restrict__ pc, int* __restrict__ sflag)
{
    __shared__ float sS[JPW*64];
    __shared__ float sR[16*68];
    __shared__ float sAdj[16*JPW];
    __shared__ float sAgg[4][16*68];

    const int blk = blockIdx.x;
    const int js = blk / 96, rem = blk % 96, b = rem / 6, it = rem % 6;
    const int tid = threadIdx.x, w = tid >> 6, l = tid & 63;
    const int quad = l >> 4, col = l & 15;
    const int j0 = js * JPW;
    const int st0 = j0 >> 4, st1 = (j0 + JPW - 1) >> 4;
    const int fb = b*6;
    const short8* wz = (const short8*)wswz;

    // ---- persistent staging (registers/LDS survive cache invalidations) ----
    for (int q = tid; q < 16*JPW; q += 256) {
        int i = q / JPW, j = q % JPW;
        sAdj[q] = adj[(b*NN + it*16 + i)*NN + j0 + j];
    }
    short8 w2f[2][4];
    #pragma unroll
    for (int kc = 0; kc < 2; kc++)
      #pragma unroll
      for (int nt = 0; nt < 4; nt++)
        w2f[kc][nt] = wz[(kc*4 + nt)*64 + l];
    float b2v[4];
    #pragma unroll
    for (int nt = 0; nt < 4; nt++) b2v[nt] = b2in[nt*16 + col];
    const int gi_row = tid >> 4, gd4 = (tid & 15) * 4;

    for (int t = 0; t < TSTEP; t++) {
        // ---- wait for S/R of step t ----
        if (t > 0 && tid == 0) {
            wait_ge(&sflag[fb + st0], t);
            wait_ge(&sflag[fb + st1], t);
            wait_ge(&sflag[fb + it], t);
            __builtin_amdgcn_fence(__ATOMIC_ACQUIRE, "agent");
        }
        __syncthreads();
        // ---- stage S rows and R+b1 rows ----
        if (t > 0) {
            for (int q = tid; q < JPW*16; q += 256) {
                int row = q >> 4, c4 = (q & 15) * 4;
                *(floatx4*)&sS[row*64 + c4] = *(const floatx4*)&Sg[(b*NN + j0 + row)*64 + c4];
            }
            for (int q = tid; q < 16*16; q += 256) {
                int row = q >> 4, c4 = (q & 15) * 4;
                floatx4 r4 = *(const floatx4*)&Rg[(b*NN + it*16 + row)*64 + c4];
                floatx4 b4 = *(const floatx4*)&b1in[c4];
                *(floatx4*)&sR[row*68 + c4] = r4 + b4;
            }
        } else {
            for (int q = tid; q < JPW*16; q += 256) {
                int row = q >> 4, c4 = (q & 15) * 4;
                floatx4 z = {0.f,0.f,0.f,0.f};
                *(floatx4*)&sS[row*64 + c4] = z;
            }
            for (int q = tid; q < 16*16; q += 256) {
                int row = q >> 4, c4 = (q & 15) * 4;
                *(floatx4*)&sR[row*68 + c4] = *(const floatx4*)&b1in[c4];
            }
        }
        __syncthreads();

        // ---- message pass: 4 waves x 3 j's ----
        float rbv[16];
        #pragma unroll
        for (int c = 0; c < 4; c++)
            *(floatx4*)&rbv[c*4] = *(const floatx4*)&sR[col*68 + (c>>1)*32 + quad*8 + (c&1)*4];

        float agg[4][4];
        #pragma unroll
        for (int nt=0;nt<4;nt++)
          #pragma unroll
          for (int r=0;r<4;r++) agg[nt][r] = 0.f;

        for (int c = 0; c < 3; c++) {
            int jl = w*3 + c;
            float sv[16];
            #pragma unroll
            for (int cc = 0; cc < 4; cc++)
                *(floatx4*)&sv[cc*4] = *(const floatx4*)&sS[jl*64 + (cc>>1)*32 + quad*8 + (cc&1)*4];
            short8 a0, a1;
            #pragma unroll
            for (int e = 0; e < 8; e++) {
                a0[e] = f2bf(fast_tanh(sv[e]   + rbv[e]));
                a1[e] = f2bf(fast_tanh(sv[8+e] + rbv[8+e]));
            }
            floatx4 acc[4];
            zero4(acc);
            #pragma unroll
            for (int nt = 0; nt < 4; nt++) {
                acc[nt] = __builtin_amdgcn_mfma_f32_16x16x32_bf16(a0, w2f[0][nt], acc[nt], 0,0,0);
                acc[nt] = __builtin_amdgcn_mfma_f32_16x16x32_bf16(a1, w2f[1][nt], acc[nt], 0,0,0);
            }
            float adjv[4];
            #pragma unroll
            for (int r = 0; r < 4; r++) adjv[r] = sAdj[(quad*4 + r)*JPW + jl];
            #pragma unroll
            for (int nt = 0; nt < 4; nt++)
              #pragma unroll
              for (int r = 0; r < 4; r++)
                agg[nt][r] += adjv[r] * fast_tanh(acc[nt][r] + b2v[nt]);
        }
        #pragma unroll
        for (int nt = 0; nt < 4; nt++)
          #pragma unroll
          for (int r = 0; r < 4; r++)
            sAgg[w][(quad*4 + r)*68 + nt*16 + col] = agg[nt][r];
        __syncthreads();
        {
            floatx4 s0 = *(const floatx4*)&sAgg[0][gi_row*68 + gd4];
            floatx4 s1 = *(const floatx4*)&sAgg[1][gi_row*68 + gd4];
            floatx4 s2 = *(const floatx4*)&sAgg[2][gi_row*68 + gd4];
            floatx4 s3 = *(const floatx4*)&sAgg[3][gi_row*68 + gd4];
            floatx4 o = ((s0 + s1) + (s2 + s3)) * (1.f/96.f);
            *(floatx4*)&partial[((js*BSZ + b)*NN + it*16 + gi_row)*64 + gd4] = o;
        }
        __syncthreads();   // drains vmcnt per wave before barrier
        if (tid == 0) {
            __builtin_amdgcn_fence(__ATOMIC_RELEASE, "agent");
            __hip_atomic_fetch_add(&pc[fb + it], 1, __ATOMIC_RELAXED, __HIP_MEMORY_SCOPE_AGENT);
        }

        // ---- GRU phase: js==0 blocks only ----
        if (js == 0) {
            if (tid == 0) {
                wait_ge(&pc[fb + it], JSPLIT*(t+1));
                __builtin_amdgcn_fence(__ATOMIC_ACQUIRE, "agent");
            }
            __syncthreads();
            floatx4 a = {0.f,0.f,0.f,0.f};
            #pragma unroll
            for (int p = 0; p < JSPLIT; p++)
                a += *(const floatx4*)&partial[((p*BSZ + b)*NN + it*16 + gi_row)*64 + gd4];
            *(floatx4*)&sAgg[0][gi_row*68 + gd4] = a;
            __syncthreads();
            if (w < 3) {          // Ar / Ai / Ah in parallel
                short8 A0, A1;
                buildA(sAgg[0], col, quad, A0, A1);
                floatx4 M[4]; zero4(M);
                mm16(A0, A1, wz + (1+w)*512, l, M);
                #pragma unroll
                for (int nt = 0; nt < 4; nt++)
                  #pragma unroll
                  for (int r = 0; r < 4; r++)
                    sAgg[1+w][(quad*4 + r)*68 + nt*16 + col] = M[nt][r];
            }
            __syncthreads();
            {                     // elementwise GRU, all 256 threads
                int s = skills[b*13 + t];
                floatx4 ar = *(const floatx4*)&sAgg[1][gi_row*68 + gd4];
                floatx4 ai = *(const floatx4*)&sAgg[2][gi_row*68 + gd4];
                floatx4 ah = *(const floatx4*)&sAgg[3][gi_row*68 + gd4];
                floatx4 er = *(const floatx4*)&Ef[0*6144 + s*64 + gd4];
                floatx4 ei = *(const floatx4*)&Ef[1*6144 + s*64 + gd4];
                floatx4 en = *(const floatx4*)&Ef[2*6144 + s*64 + gd4];
                floatx4 hold = {0.f,0.f,0.f,0.f};
                if (t > 0)
                    hold = *(const floatx4*)&Hall[(((t-1)*BSZ + b)*NN + it*16 + gi_row)*64 + gd4];
                floatx4 h;
                #pragma unroll
                for (int e = 0; e < 4; e++) {
                    float gr  = fast_sigmoid(er[e] + ar[e]);
                    float gi2 = fast_sigmoid(ei[e] + ai[e]);
                    float nn2 = fast_tanh(en[e] + gr * ah[e]);
                    h[e] = (1.f - gi2)*nn2 + gi2*hold[e];
                }
                *(floatx4*)&Hall[((t*BSZ + b)*NN + it*16 + gi_row)*64 + gd4] = h;
                *(floatx4*)&sAgg[0][gi_row*68 + gd4] = h;
            }
            __syncthreads();
            if (w < 2) {          // S (w==0) / R (w==1) in parallel
                short8 h0, h1;
                buildA(sAgg[0], col, quad, h0, h1);
                floatx4 M[4]; zero4(M);
                mm16(h0, h1, wz + (4+w)*512, l, M);
                float* dst = (w == 0) ? Sg : Rg;
                #pragma unroll
                for (int nt = 0; nt < 4; nt++)
                  #pragma unroll
                  for (int r = 0; r < 4; r++)
                    dst[(b*NN + it*16 + quad*4 + r)*64 + nt*16 + col] = M[nt][r];
            }
            __syncthreads();
            if (tid == 0) {
                __builtin_amdgcn_fence(__ATOMIC_RELEASE, "agent");
                __hip_atomic_store(&sflag[fb + it], t+1, __ATOMIC_RELAXED, __HIP_MEMORY_SCOPE_AGENT);
            }
        }
    }

    // ---- deferred output MLPs: js<3 blocks, one (t,b,it) tile per wave ----
    if (js < 3) {
        if (tid == 0) {
            wait_ge(&sflag[fb + it], TSTEP);
            __builtin_amdgcn_fence(__ATOMIC_ACQUIRE, "agent");
        }
        __syncthreads();
        const int t2 = js*4 + w;
        float* sT = sAgg[w];
        short8 x0, x1;
        floatx4 O[4];
        {
            const float* hb = &Hall[((t2*BSZ + b)*NN + it*16 + col)*64];
            floatx4 f0 = *(const floatx4*)&hb[quad*8];
            floatx4 f1 = *(const floatx4*)&hb[quad*8 + 4];
            floatx4 f2 = *(const floatx4*)&hb[32 + quad*8];
            floatx4 f3 = *(const floatx4*)&hb[32 + quad*8 + 4];
            #pragma unroll
            for (int jj = 0; jj < 4; jj++){
                x0[jj]   = f2bf(f0[jj]);
                x0[4+jj] = f2bf(f1[jj]);
                x1[jj]   = f2bf(f2[jj]);
                x1[4+jj] = f2bf(f3[jj]);
            }
            zero4(O);
            mm16(x0, x1, wz + 6*512, l, O);
            #pragma unroll
            for (int nt = 0; nt < 4; nt++)
              #pragma unroll
              for (int r = 0; r < 4; r++)
                sT[(quad*4 + r)*68 + nt*16 + col] = fmaxf(0.f, O[nt][r] + bo1[nt*16 + col]);
        }
        __syncthreads();
        buildA(sT, col, quad, x0, x1);
        zero4(O);
        mm16(x0, x1, wz + 7*512, l, O);
        __syncthreads();
        #pragma unroll
        for (int nt = 0; nt < 4; nt++)
          #pragma unroll
          for (int r = 0; r < 4; r++)
            sT[(quad*4 + r)*68 + nt*16 + col] = fmaxf(0.f, O[nt][r] + bo2[nt*16 + col]);
        __syncthreads();
        buildA(sT, col, quad, x0, x1);
        zero4(O);
        mm16(x0, x1, wz + 8*512, l, O);
        #pragma unroll
        for (int nt = 0; nt < 4; nt++)
          #pragma unroll
          for (int r = 0; r < 4; r++) {
            int d = nt*16 + col;
            int row = quad*4 + r;
            out[((b*TSTEP + t2)*NN + it*16 + row)*64 + d] = O[nt][r] + bo3[d];
          }
    }
}

extern "C" void kernel_launch(void* const* d_in, const int* in_sizes, int n_in,
                              void* d_out, int out_size, void* d_ws, size_t ws_size,
                              hipStream_t stream) {
    const int*   skills = (const int*)d_in[0];
    const float* adj    = (const float*)d_in[1];
    const float* emb    = (const float*)d_in[2];
    const float* Wmsg1  = (const float*)d_in[3];
    const float* b1     = (const float*)d_in[4];
    const float* Wmsg2  = (const float*)d_in[5];
    const float* b2     = (const float*)d_in[6];
    const float* Whr    = (const float*)d_in[7];
    const float* Whi    = (const float*)d_in[8];
    const float* Whh    = (const float*)d_in[9];
    const float* Wir    = (const float*)d_in[10];
    const float* bir    = (const float*)d_in[11];
    const float* Wii    = (const float*)d_in[12];
    const float* bii    = (const float*)d_in[13];
    const float* Win    = (const float*)d_in[14];
    const float* bin    = (const float*)d_in[15];
    const float* Wo1    = (const float*)d_in[16];
    const float* bo1    = (const float*)d_in[17];
    const float* Wo2    = (const float*)d_in[18];
    const float* bo2    = (const float*)d_in[19];
    const float* Wo3    = (const float*)d_in[20];
    const float* bo3    = (const float*)d_in[21];

    char* ws = (char*)d_ws;
    int*      flags   = (int*)(ws + OFF_FLAG);
    int*      pc      = flags;
    int*      sflag   = flags + 96;
    float*    Sg      = (float*)(ws + OFF_S);
    float*    Rg      = (float*)(ws + OFF_R);
    float*    Ef      = (float*)(ws + OFF_E);
    float*    partial = (float*)(ws + OFF_P);
    float*    Hall    = (float*)(ws + OFF_HALL);
    ushort_t* wswz    = (ushort_t*)(ws + OFF_WSWZ);
    float*    out     = (float*)d_out;

    k_init<<<dim3(217), dim3(256), 0, stream>>>(emb, Wmsg1, Wmsg2, Whr, Whi, Whh,
        Wir, bir, Wii, bii, Win, bin, Wo1, Wo2, Wo3, flags, Ef, wswz);

    k_loop<<<dim3(NBLK), dim3(256), 0, stream>>>(
        skills, adj, b1, b2, bo1, bo2, bo3, Ef, wswz,
        Sg, Rg, partial, Hall, out, pc, sflag);
}

// Round 7
// 346.772 us; speedup vs baseline: 3.8721x; 1.4783x over previous
//
#include <hip/hip_runtime.h>

typedef unsigned short ushort_t;
typedef __attribute__((ext_vector_type(8))) short short8;
typedef __attribute__((ext_vector_type(4))) float floatx4;

#define NN 96
#define BSZ 16
#define TSTEP 12
#define JSPLIT 4
#define JPW 24   /* 96 / JSPLIT */
#define NBLK 384 /* 4 x 16 x 6; needs only 1.5 blocks/CU residency */

// workspace offsets (bytes)
#define OFF_FLAG  0u        /* pc[96] + sflag[96] ints */
#define OFF_S     1024u
#define OFF_R     394240u
#define OFF_E     787456u
#define OFF_P     861184u
#define OFF_HALL  4006912u
#define OFF_WSWZ  8725504u

static __device__ __forceinline__ short f2bf(float f){
    union { float f; unsigned u; } v; v.f = f;
    unsigned u = v.u;
    u += 0x7fffu + ((u >> 16) & 1u);   // RNE
    return (short)(u >> 16);
}
static __device__ __forceinline__ float fast_tanh(float x){
    x = fminf(20.f, fmaxf(-20.f, x));
    float p = __expf(2.f * x);
    return (p - 1.f) * __builtin_amdgcn_rcpf(p + 1.f);
}
static __device__ __forceinline__ float fast_sigmoid(float x){
    x = fminf(30.f, fmaxf(-30.f, x));
    float p = __expf(-x);
    return __builtin_amdgcn_rcpf(1.f + p);
}
static __device__ __forceinline__ void zero4(floatx4* a){
    floatx4 z = {0.f,0.f,0.f,0.f};
    a[0]=z; a[1]=z; a[2]=z; a[3]=z;
}
// device-coherent payload access (LLC-level, no fences needed)
static __device__ __forceinline__ float ld_dev(const float* p){
    return __hip_atomic_load(p, __ATOMIC_RELAXED, __HIP_MEMORY_SCOPE_AGENT);
}
static __device__ __forceinline__ void st_dev(float* p, float v){
    __hip_atomic_store(p, v, __ATOMIC_RELAXED, __HIP_MEMORY_SCOPE_AGENT);
}
static __device__ __forceinline__ void wait_ge(int* f, int target){
    while (__hip_atomic_load(f, __ATOMIC_RELAXED, __HIP_MEMORY_SCOPE_AGENT) < target)
        __builtin_amdgcn_s_sleep(2);
}
// read A-fragments (16x64, row m = lane&15, k = quad*8+jj) from LDS tile, stride 68
static __device__ __forceinline__ void buildA(const float* sM, int col, int quad, short8& a0, short8& a1){
    floatx4 f0 = *(const floatx4*)&sM[col*68 + quad*8];
    floatx4 f1 = *(const floatx4*)&sM[col*68 + quad*8 + 4];
    floatx4 f2 = *(const floatx4*)&sM[col*68 + 32 + quad*8];
    floatx4 f3 = *(const floatx4*)&sM[col*68 + 32 + quad*8 + 4];
    #pragma unroll
    for (int jj = 0; jj < 4; jj++){
        a0[jj]   = f2bf(f0[jj]);
        a0[4+jj] = f2bf(f1[jj]);
        a1[jj]   = f2bf(f2[jj]);
        a1[4+jj] = f2bf(f3[jj]);
    }
}
// 16x64 = (16x64) @ (64x64), B pre-swizzled fragment-major; accumulates into acc[4]
static __device__ __forceinline__ void mm16(short8 a0, short8 a1, const short8* wzm, int l, floatx4* acc){
    #pragma unroll
    for (int nt = 0; nt < 4; nt++){
        short8 b0 = wzm[nt*64 + l];
        short8 b1 = wzm[(4 + nt)*64 + l];
        acc[nt] = __builtin_amdgcn_mfma_f32_16x16x32_bf16(a0, b0, acc[nt], 0, 0, 0);
        acc[nt] = __builtin_amdgcn_mfma_f32_16x16x32_bf16(a1, b1, acc[nt], 0, 0, 0);
    }
}

// ---------------------------------------------------------------------------
// init: zero flags, compute E_* = emb @ W_i* + b_* (fp32), pre-swizzle 9
// weight matrices into bf16 B-fragment order: flat = ((kc*4+nt)*64 + lane)*8 + jj
// ---------------------------------------------------------------------------
__global__ __launch_bounds__(256) void k_init(
    const float* __restrict__ emb, const float* __restrict__ Wmsg1,
    const float* __restrict__ Wmsg2,
    const float* __restrict__ Whr, const float* __restrict__ Whi, const float* __restrict__ Whh,
    const float* __restrict__ Wir, const float* __restrict__ bir,
    const float* __restrict__ Wii, const float* __restrict__ bii,
    const float* __restrict__ Win, const float* __restrict__ bin,
    const float* __restrict__ Wo1, const float* __restrict__ Wo2, const float* __restrict__ Wo3,
    int* __restrict__ flags, float* __restrict__ Ef, ushort_t* __restrict__ wswz)
{
    int wg = blockIdx.x, tid = threadIdx.x;
    if (wg == 0) {                        // zero pc[96] + sflag[96] (device-visible)
        if (tid < 192)
            __hip_atomic_store(&flags[tid], 0, __ATOMIC_RELAXED, __HIP_MEMORY_SCOPE_AGENT);
    } else if (wg < 73) {                 // E matrices: 3 * 96 * 64
        int flat = (wg - 1)*256 + tid;
        int m = flat / 6144; int r = flat % 6144; int s = r >> 6; int d = r & 63;
        const float* W = (m==0)? Wir : (m==1)? Wii : Win;
        const float* B = (m==0)? bir : (m==1)? bii : bin;
        float acc = B[d];
        #pragma unroll 8
        for (int k = 0; k < 64; k++)
            acc += emb[s*64 + k] * W[k*64 + d];
        Ef[flat] = acc;
    } else {                              // swizzle: 9 * 4096
        int flat = (wg - 73)*256 + tid;
        int m = flat >> 12; int q = flat & 4095;
        int jj = q & 7, lane = (q >> 3) & 63, nt = (q >> 9) & 3, kc = q >> 11;
        int k = kc*32 + ((lane >> 4) << 3) + jj;
        int n = nt*16 + (lane & 15);
        const float* src; int idx = k*64 + n;
        switch (m) {
          case 0: src = Wmsg2; break;
          case 1: src = Whr;  break;
          case 2: src = Whi;  break;
          case 3: src = Whh;  break;
          case 4: src = Wmsg1; break;
          case 5: src = Wmsg1; idx = (64 + k)*64 + n; break;
          case 6: src = Wo1; break;
          case 7: src = Wo2; break;
          default: src = Wo3; break;
        }
        wswz[flat] = (ushort_t)f2bf(src[idx]);
    }
}

// ---------------------------------------------------------------------------
// persistent kernel, flag-synced, fence-free (payload via device-coherent
// relaxed atomics). 384 blocks = 4(js) x 16(b) x 6(it). Per step:
//   msg: wait sflag(2 S tiles, R tile) >= t; compute; st_dev partial; pc += 1
//   GRU (js==0): wait pc >= 4(t+1); GRU (h in registers); st_dev Hall/Sg/Rg;
//                sflag = t+1
// MLP tail: js<3 blocks wait sflag >= 12; one (t,b,it) tile per wave.
// ---------------------------------------------------------------------------
__global__ __launch_bounds__(256, 2) void k_loop(
    const int* __restrict__ skills, const float* __restrict__ adj,
    const float* __restrict__ b1in, const float* __restrict__ b2in,
    const float* __restrict__ bo1, const float* __restrict__ bo2, const float* __restrict__ bo3,
    const float* __restrict__ Ef, const ushort_t* __restrict__ wswz,
    float* __restrict__ Sg, float* __restrict__ Rg, float* __restrict__ partial,
    float* __restrict__ Hall, float* __restrict__ out,
    int* __restrict__ pc, int* __restrict__ sflag)
{
    __shared__ float sS[JPW*64];
    __shared__ float sR[16*68];
    __shared__ float sAdj[16*JPW];
    __shared__ float sAgg[4][16*68];

    const int blk = blockIdx.x;
    const int js = blk / 96, rem = blk % 96, b = rem / 6, it = rem % 6;
    const int tid = threadIdx.x, w = tid >> 6, l = tid & 63;
    const int quad = l >> 4, col = l & 15;
    const int j0 = js * JPW;
    const int st0 = j0 >> 4, st1 = (j0 + JPW - 1) >> 4;
    const int fb = b*6;
    const short8* wz = (const short8*)wswz;

    // ---- persistent staging (LDS/registers survive across steps) ----
    for (int q = tid; q < 16*JPW; q += 256) {
        int i = q / JPW, j = q % JPW;
        sAdj[q] = adj[(b*NN + it*16 + i)*NN + j0 + j];
    }
    short8 w2f[2][4];
    #pragma unroll
    for (int kc = 0; kc < 2; kc++)
      #pragma unroll
      for (int nt = 0; nt < 4; nt++)
        w2f[kc][nt] = wz[(kc*4 + nt)*64 + l];
    float b2v[4];
    #pragma unroll
    for (int nt = 0; nt < 4; nt++) b2v[nt] = b2in[nt*16 + col];
    const int gi_row = tid >> 4, gd4 = (tid & 15) * 4;
    floatx4 hreg = {0.f,0.f,0.f,0.f};   // js==0: persistent hidden slice (row=gi_row, d=gd4..+3)

    for (int t = 0; t < TSTEP; t++) {
        // ---- wait for S/R of step t ----
        if (t > 0 && tid == 0) {
            wait_ge(&sflag[fb + st0], t);
            wait_ge(&sflag[fb + st1], t);
            wait_ge(&sflag[fb + it], t);
        }
        __syncthreads();
        // ---- stage S rows and R+b1 rows (device-coherent loads) ----
        if (t > 0) {
            for (int q = tid; q < JPW*64; q += 256)
                sS[q] = ld_dev(&Sg[(b*NN + j0)*64 + q]);
            for (int q = tid; q < 16*64; q += 256) {
                int row = q >> 6, c = q & 63;
                sR[row*68 + c] = ld_dev(&Rg[(b*NN + it*16 + row)*64 + c]) + b1in[c];
            }
        } else {
            for (int q = tid; q < JPW*64; q += 256)
                sS[q] = 0.f;
            for (int q = tid; q < 16*64; q += 256) {
                int row = q >> 6, c = q & 63;
                sR[row*68 + c] = b1in[c];
            }
        }
        __syncthreads();

        // ---- message pass: 4 waves x 6 j's ----
        float rbv[16];
        #pragma unroll
        for (int c = 0; c < 4; c++)
            *(floatx4*)&rbv[c*4] = *(const floatx4*)&sR[col*68 + (c>>1)*32 + quad*8 + (c&1)*4];

        float agg[4][4];
        #pragma unroll
        for (int nt=0;nt<4;nt++)
          #pragma unroll
          for (int r=0;r<4;r++) agg[nt][r] = 0.f;

        for (int c = 0; c < 6; c++) {
            int jl = w*6 + c;
            float sv[16];
            #pragma unroll
            for (int cc = 0; cc < 4; cc++)
                *(floatx4*)&sv[cc*4] = *(const floatx4*)&sS[jl*64 + (cc>>1)*32 + quad*8 + (cc&1)*4];
            short8 a0, a1;
            #pragma unroll
            for (int e = 0; e < 8; e++) {
                a0[e] = f2bf(fast_tanh(sv[e]   + rbv[e]));
                a1[e] = f2bf(fast_tanh(sv[8+e] + rbv[8+e]));
            }
            floatx4 acc[4];
            zero4(acc);
            #pragma unroll
            for (int nt = 0; nt < 4; nt++) {
                acc[nt] = __builtin_amdgcn_mfma_f32_16x16x32_bf16(a0, w2f[0][nt], acc[nt], 0,0,0);
                acc[nt] = __builtin_amdgcn_mfma_f32_16x16x32_bf16(a1, w2f[1][nt], acc[nt], 0,0,0);
            }
            float adjv[4];
            #pragma unroll
            for (int r = 0; r < 4; r++) adjv[r] = sAdj[(quad*4 + r)*JPW + jl];
            #pragma unroll
            for (int nt = 0; nt < 4; nt++)
              #pragma unroll
              for (int r = 0; r < 4; r++)
                agg[nt][r] += adjv[r] * fast_tanh(acc[nt][r] + b2v[nt]);
        }
        #pragma unroll
        for (int nt = 0; nt < 4; nt++)
          #pragma unroll
          for (int r = 0; r < 4; r++)
            sAgg[w][(quad*4 + r)*68 + nt*16 + col] = agg[nt][r];
        __syncthreads();
        {
            floatx4 s0 = *(const floatx4*)&sAgg[0][gi_row*68 + gd4];
            floatx4 s1 = *(const floatx4*)&sAgg[1][gi_row*68 + gd4];
            floatx4 s2 = *(const floatx4*)&sAgg[2][gi_row*68 + gd4];
            floatx4 s3 = *(const floatx4*)&sAgg[3][gi_row*68 + gd4];
            floatx4 o = ((s0 + s1) + (s2 + s3)) * (1.f/96.f);
            float* dst = &partial[((js*BSZ + b)*NN + it*16 + gi_row)*64 + gd4];
            #pragma unroll
            for (int e = 0; e < 4; e++) st_dev(&dst[e], o[e]);
        }
        __syncthreads();   // drains vmcnt (all partial stores at LLC) before flag
        if (tid == 0)
            __hip_atomic_fetch_add(&pc[fb + it], 1, __ATOMIC_RELAXED, __HIP_MEMORY_SCOPE_AGENT);

        // ---- GRU phase: js==0 blocks only ----
        if (js == 0) {
            if (tid == 0)
                wait_ge(&pc[fb + it], JSPLIT*(t+1));
            __syncthreads();
            floatx4 a = {0.f,0.f,0.f,0.f};
            #pragma unroll
            for (int p = 0; p < JSPLIT; p++) {
                const float* src = &partial[((p*BSZ + b)*NN + it*16 + gi_row)*64 + gd4];
                #pragma unroll
                for (int e = 0; e < 4; e++) a[e] += ld_dev(&src[e]);
            }
            *(floatx4*)&sAgg[0][gi_row*68 + gd4] = a;
            __syncthreads();
            if (w < 3) {          // Ar / Ai / Ah in parallel
                short8 A0, A1;
                buildA(sAgg[0], col, quad, A0, A1);
                floatx4 M[4]; zero4(M);
                mm16(A0, A1, wz + (1+w)*512, l, M);
                #pragma unroll
                for (int nt = 0; nt < 4; nt++)
                  #pragma unroll
                  for (int r = 0; r < 4; r++)
                    sAgg[1+w][(quad*4 + r)*68 + nt*16 + col] = M[nt][r];
            }
            __syncthreads();
            {                     // elementwise GRU, all 256 threads; h in registers
                int s = skills[b*13 + t];
                floatx4 ar = *(const floatx4*)&sAgg[1][gi_row*68 + gd4];
                floatx4 ai = *(const floatx4*)&sAgg[2][gi_row*68 + gd4];
                floatx4 ah = *(const floatx4*)&sAgg[3][gi_row*68 + gd4];
                floatx4 er = *(const floatx4*)&Ef[0*6144 + s*64 + gd4];
                floatx4 ei = *(const floatx4*)&Ef[1*6144 + s*64 + gd4];
                floatx4 en = *(const floatx4*)&Ef[2*6144 + s*64 + gd4];
                floatx4 h;
                #pragma unroll
                for (int e = 0; e < 4; e++) {
                    float gr  = fast_sigmoid(er[e] + ar[e]);
                    float gi2 = fast_sigmoid(ei[e] + ai[e]);
                    float nn2 = fast_tanh(en[e] + gr * ah[e]);
                    h[e] = (1.f - gi2)*nn2 + gi2*hreg[e];
                }
                hreg = h;
                float* hd = &Hall[((t*BSZ + b)*NN + it*16 + gi_row)*64 + gd4];
                #pragma unroll
                for (int e = 0; e < 4; e++) st_dev(&hd[e], h[e]);
                *(floatx4*)&sAgg[0][gi_row*68 + gd4] = h;
            }
            __syncthreads();
            if (w < 2) {          // S (w==0) / R (w==1) in parallel
                short8 h0, h1;
                buildA(sAgg[0], col, quad, h0, h1);
                floatx4 M[4]; zero4(M);
                mm16(h0, h1, wz + (4+w)*512, l, M);
                float* dstb = (w == 0) ? Sg : Rg;
                #pragma unroll
                for (int nt = 0; nt < 4; nt++)
                  #pragma unroll
                  for (int r = 0; r < 4; r++)
                    st_dev(&dstb[(b*NN + it*16 + quad*4 + r)*64 + nt*16 + col], M[nt][r]);
            }
            __syncthreads();      // drains Hall/Sg/Rg stores before flag
            if (tid == 0)
                __hip_atomic_store(&sflag[fb + it], t+1, __ATOMIC_RELAXED, __HIP_MEMORY_SCOPE_AGENT);
        }
    }

    // ---- deferred output MLPs: js<3 blocks, one (t,b,it) tile per wave ----
    if (js < 3) {
        if (tid == 0)
            wait_ge(&sflag[fb + it], TSTEP);
        __syncthreads();
        const int t2 = js*4 + w;
        float* sT = sAgg[w];
        short8 x0, x1;
        floatx4 O[4];
        {
            const float* hb = &Hall[((t2*BSZ + b)*NN + it*16 + col)*64];
            float hv[16];
            #pragma unroll
            for (int e = 0; e < 8; e++) {
                hv[e]   = ld_dev(&hb[quad*8 + e]);
                hv[8+e] = ld_dev(&hb[32 + quad*8 + e]);
            }
            #pragma unroll
            for (int e = 0; e < 8; e++) {
                x0[e] = f2bf(hv[e]);
                x1[e] = f2bf(hv[8+e]);
            }
            zero4(O);
            mm16(x0, x1, wz + 6*512, l, O);
            #pragma unroll
            for (int nt = 0; nt < 4; nt++)
              #pragma unroll
              for (int r = 0; r < 4; r++)
                sT[(quad*4 + r)*68 + nt*16 + col] = fmaxf(0.f, O[nt][r] + bo1[nt*16 + col]);
        }
        __syncthreads();
        buildA(sT, col, quad, x0, x1);
        zero4(O);
        mm16(x0, x1, wz + 7*512, l, O);
        __syncthreads();
        #pragma unroll
        for (int nt = 0; nt < 4; nt++)
          #pragma unroll
          for (int r = 0; r < 4; r++)
            sT[(quad*4 + r)*68 + nt*16 + col] = fmaxf(0.f, O[nt][r] + bo2[nt*16 + col]);
        __syncthreads();
        buildA(sT, col, quad, x0, x1);
        zero4(O);
        mm16(x0, x1, wz + 8*512, l, O);
        #pragma unroll
        for (int nt = 0; nt < 4; nt++)
          #pragma unroll
          for (int r = 0; r < 4; r++) {
            int d = nt*16 + col;
            int row = quad*4 + r;
            out[((b*TSTEP + t2)*NN + it*16 + row)*64 + d] = O[nt][r] + bo3[d];
          }
    }
}

extern "C" void kernel_launch(void* const* d_in, const int* in_sizes, int n_in,
                              void* d_out, int out_size, void* d_ws, size_t ws_size,
                              hipStream_t stream) {
    const int*   skills = (const int*)d_in[0];
    const float* adj    = (const float*)d_in[1];
    const float* emb    = (const float*)d_in[2];
    const float* Wmsg1  = (const float*)d_in[3];
    const float* b1     = (const float*)d_in[4];
    const float* Wmsg2  = (const float*)d_in[5];
    const float* b2     = (const float*)d_in[6];
    const float* Whr    = (const float*)d_in[7];
    const float* Whi    = (const float*)d_in[8];
    const float* Whh    = (const float*)d_in[9];
    const float* Wir    = (const float*)d_in[10];
    const float* bir    = (const float*)d_in[11];
    const float* Wii    = (const float*)d_in[12];
    const float* bii    = (const float*)d_in[13];
    const float* Win    = (const float*)d_in[14];
    const float* bin    = (const float*)d_in[15];
    const float* Wo1    = (const float*)d_in[16];
    const float* bo1    = (const float*)d_in[17];
    const float* Wo2    = (const float*)d_in[18];
    const float* bo2    = (const float*)d_in[19];
    const float* Wo3    = (const float*)d_in[20];
    const float* bo3    = (const float*)d_in[21];

    char* ws = (char*)d_ws;
    int*      flags   = (int*)(ws + OFF_FLAG);
    int*      pc      = flags;
    int*      sflag   = flags + 96;
    float*    Sg      = (float*)(ws + OFF_S);
    float*    Rg      = (float*)(ws + OFF_R);
    float*    Ef      = (float*)(ws + OFF_E);
    float*    partial = (float*)(ws + OFF_P);
    float*    Hall    = (float*)(ws + OFF_HALL);
    ushort_t* wswz    = (ushort_t*)(ws + OFF_WSWZ);
    float*    out     = (float*)d_out;

    k_init<<<dim3(217), dim3(256), 0, stream>>>(emb, Wmsg1, Wmsg2, Whr, Whi, Whh,
        Wir, bir, Wii, bii, Win, bin, Wo1, Wo2, Wo3, flags, Ef, wswz);

    k_loop<<<dim3(NBLK), dim3(256), 0, stream>>>(
        skills, adj, b1, b2, bo1, bo2, bo3, Ef, wswz,
        Sg, Rg, partial, Hall, out, pc, sflag);
}